// Round 2
// baseline (3018.290 us; speedup 1.0000x reference)
//
#include <hip/hip_runtime.h>
#include <stdint.h>
#include <math.h>

constexpr int BB = 16;      // batch
constexpr int NN = 4096;    // points per batch
constexpr int SS = 1024;    // centroids (N_CENTROIDS)
constexpr int KK = 32;      // NSAMPLES
constexpr int C3 = 128;     // mlp1
constexpr float R2 = 0.25f; // RADIUS^2
constexpr int STAT_BLOCKS = 2048;  // blocks for stats kernels (8 groups each)

// exact-order (a0*a0 + a1*a1) + a2*a2, no fma contraction (matches np sum over 3)
__device__ __forceinline__ float sumsq3(float x, float y, float z) {
#pragma clang fp contract(off)
  return (x * x + y * y) + z * z;
}

// exact-order GEMM-form squared distance: (aa + bb) - 2*((cx*px+cy*py)+cz*pz)
__device__ __forceinline__ float ball_d(float aa, float bb, float cx, float cy,
                                        float cz, float px, float py, float pz) {
#pragma clang fp contract(off)
  float ab = (cx * px + cy * py) + cz * pz;
  return (aa + bb) - 2.0f * ab;
}

// ---------------- bb precompute: per-point squared norms ----------------
__global__ void k_bb(const float* __restrict__ x, float* __restrict__ bb) {
  int i = blockIdx.x * blockDim.x + threadIdx.x;
  if (i >= BB * NN) return;
  float x0 = x[3 * i], x1 = x[3 * i + 1], x2 = x[3 * i + 2];
  bb[i] = sumsq3(x0, x1, x2);
}

// ---------------- FPS: one block per batch, sequential 1024 picks ----------------
__global__ __launch_bounds__(1024) void k_fps(const float* __restrict__ x,
                                              int* __restrict__ cidx) {
  __shared__ float xs[NN], ys[NN], zs[NN];
  __shared__ float wv[2][16];
  __shared__ int wi[2][16];
  int b = blockIdx.x, t = threadIdx.x;
  const float* xb = x + (size_t)b * NN * 3;
  for (int n = t; n < NN; n += 1024) {
    xs[n] = xb[3 * n];
    ys[n] = xb[3 * n + 1];
    zs[n] = xb[3 * n + 2];
  }
  if (t == 0) cidx[b * SS] = 0;
  float dmin[4] = {1e10f, 1e10f, 1e10f, 1e10f};
  __syncthreads();

  int far = 0;
  int w = t >> 6, lane = t & 63;
  for (int it = 1; it < SS; ++it) {
    float cx = xs[far], cy = ys[far], cz = zs[far];
    float best = -1.0f;
    int bi = NN;
#pragma unroll
    for (int j = 0; j < 4; ++j) {
      int n = t + j * 1024;
      float dx = xs[n] - cx, dy = ys[n] - cy, dz = zs[n] - cz;
      float d = sumsq3(dx, dy, dz);
      float dm = fminf(dmin[j], d);
      dmin[j] = dm;
      if (dm > best) { best = dm; bi = n; }   // strictly greater keeps earliest n
    }
    // wave argmax-reduce (max value, min index on ties)
#pragma unroll
    for (int off = 1; off < 64; off <<= 1) {
      float ov = __shfl_xor(best, off);
      int oi = __shfl_xor(bi, off);
      if (ov > best || (ov == best && oi < bi)) { best = ov; bi = oi; }
    }
    int buf = it & 1;
    if (lane == 0) { wv[buf][w] = best; wi[buf][w] = bi; }
    __syncthreads();
    // redundant cross-wave reduce in every thread (deterministic, single barrier/iter)
    float gv = wv[buf][0];
    int gi = wi[buf][0];
#pragma unroll
    for (int ww = 1; ww < 16; ++ww) {
      float v = wv[buf][ww];
      int ii = wi[buf][ww];
      if (v > gv || (v == gv && ii < gi)) { gv = v; gi = ii; }
    }
    far = gi;
    if (t == 0) cidx[b * SS + it] = gi;
  }
}

// ---------------- gather centroids to d_out (f32) + squared norms ----------------
__global__ void k_gather(const float* __restrict__ x, const int* __restrict__ cidx,
                         float* __restrict__ outc, float* __restrict__ aa) {
  int i = blockIdx.x * blockDim.x + threadIdx.x;
  if (i >= BB * SS) return;
  int b = i >> 10;
  int n = cidx[i];
  const float* p = x + ((size_t)b * NN + n) * 3;
  float cx = p[0], cy = p[1], cz = p[2];
  outc[3 * i] = cx; outc[3 * i + 1] = cy; outc[3 * i + 2] = cz;
  aa[i] = sumsq3(cx, cy, cz);
}

// ---------------- ball query: one wave per (b,s) ----------------
__global__ __launch_bounds__(256) void k_ball(const float* __restrict__ x,
                                              const float* __restrict__ cent,
                                              const float* __restrict__ aa,
                                              const float* __restrict__ bb,
                                              int* __restrict__ idx) {
  int gw = (blockIdx.x * 256 + threadIdx.x) >> 6;  // 0..16383
  int lane = threadIdx.x & 63;
  if (gw >= BB * SS) return;
  int b = gw >> 10;
  const float* xb = x + (size_t)b * NN * 3;
  const float* bbb = bb + b * NN;
  float cx = cent[3 * gw], cy = cent[3 * gw + 1], cz = cent[3 * gw + 2];
  float a = aa[gw];
  int* out = idx + (size_t)gw * KK;
  int found = 0, firstN = 0;
  for (int c0 = 0; c0 < NN && found < KK; c0 += 64) {
    int n = c0 + lane;
    float px = xb[3 * n], py = xb[3 * n + 1], pz = xb[3 * n + 2];
    float d = ball_d(a, bbb[n], cx, cy, cz, px, py, pz);
    bool pred = (d <= R2);  // reference excludes d > r^2
    unsigned long long m = __ballot(pred);
    if (found == 0 && m) firstN = c0 + (__ffsll((unsigned long long)m) - 1);
    if (pred) {
      int pos = found + __popcll(m & ((1ull << lane) - 1ull));
      if (pos < KK) out[pos] = n;
    }
    found += __popcll(m);
  }
  if (lane == 0 && found < KK) {
    for (int k = found; k < KK; ++k) out[k] = firstN;
  }
}

// ---------------- stats for BN1: conv1 over all groups, per-channel sum/sumsq ----------------
__global__ __launch_bounds__(256) void k_stats1(
    const float* __restrict__ x, const float* __restrict__ pts,
    const float* __restrict__ cent, const int* __restrict__ idx,
    const float* __restrict__ w1, const float* __restrict__ b1,
    float* __restrict__ partial1) {
  __shared__ float feat[KK][6];
  __shared__ float red[4][64][2];
  int t = threadIdx.x;
  int c = t & 63, kq = t >> 6;
  float w[6];
#pragma unroll
  for (int j = 0; j < 6; ++j) w[j] = w1[c * 6 + j];
  float bias = b1[c];
  float sum = 0.f, sq = 0.f;
  for (int gi = 0; gi < 8; ++gi) {
    int g = blockIdx.x * 8 + gi;
    int b = g >> 10;
    if (t < KK) {
      int n = idx[(size_t)g * KK + t];
      const float* p = x + ((size_t)b * NN + n) * 3;
      feat[t][0] = p[0] - cent[3 * g];
      feat[t][1] = p[1] - cent[3 * g + 1];
      feat[t][2] = p[2] - cent[3 * g + 2];
      const float* q = pts + ((size_t)b * NN + n) * 3;
      feat[t][3] = q[0];
      feat[t][4] = q[1];
      feat[t][5] = q[2];
    }
    __syncthreads();
    for (int k = kq * 8; k < kq * 8 + 8; ++k) {
      float a = bias;
#pragma unroll
      for (int j = 0; j < 6; ++j) a += w[j] * feat[k][j];
      sum += a;
      sq += a * a;
    }
    __syncthreads();
  }
  red[kq][c][0] = sum;
  red[kq][c][1] = sq;
  __syncthreads();
  if (t < 64) {
    float s = ((red[0][t][0] + red[1][t][0]) + red[2][t][0]) + red[3][t][0];
    float q = ((red[0][t][1] + red[1][t][1]) + red[2][t][1]) + red[3][t][1];
    partial1[(size_t)(blockIdx.x * 64 + t) * 2] = s;
    partial1[(size_t)(blockIdx.x * 64 + t) * 2 + 1] = q;
  }
}

// ---------------- finalize BN1 scale/shift ----------------
__global__ void k_red1(const float* __restrict__ partial1,
                       const float* __restrict__ gamma, const float* __restrict__ beta,
                       float* __restrict__ sc1) {
  int c = threadIdx.x;
  if (c >= 64) return;
  double s = 0.0, q = 0.0;
  for (int blk = 0; blk < STAT_BLOCKS; ++blk) {
    s += partial1[(size_t)(blk * 64 + c) * 2];
    q += partial1[(size_t)(blk * 64 + c) * 2 + 1];
  }
  const double cnt = (double)BB * KK * SS;
  double mean = s / cnt;
  double var = q / cnt - mean * mean;
  float scale = gamma[c] * (float)(1.0 / sqrt(var + 1e-5));
  float shift = beta[c] - (float)mean * scale;
  sc1[c] = scale;
  sc1[64 + c] = shift;
}

// ---------------- stats for BN2: recompute conv1+BN1+ReLU, conv2, sum/sumsq ----------------
__global__ __launch_bounds__(256) void k_stats2(
    const float* __restrict__ x, const float* __restrict__ pts,
    const float* __restrict__ cent, const int* __restrict__ idx,
    const float* __restrict__ w1, const float* __restrict__ b1,
    const float* __restrict__ sc1, const float* __restrict__ w2,
    const float* __restrict__ b2, float* __restrict__ partial2) {
  __shared__ float feat[KK][6];
  __shared__ float vT[64][36];   // [c1][k], padded rows (144B, 16B-aligned)
  __shared__ float red[128][2][2];
  int t = threadIdx.x;
  int c1 = t & 63, kq = t >> 6;
  int c2 = t & 127, kh = t >> 7;
  float w1r[6];
#pragma unroll
  for (int j = 0; j < 6; ++j) w1r[j] = w1[c1 * 6 + j];
  float bias1 = b1[c1];
  float scale1 = sc1[c1], shift1 = sc1[64 + c1];
  float w2r[64];
#pragma unroll
  for (int c = 0; c < 64; ++c) w2r[c] = w2[c2 * 64 + c];
  float bias2 = b2[c2];
  float sum = 0.f, sq = 0.f;
  for (int gi = 0; gi < 8; ++gi) {
    int g = blockIdx.x * 8 + gi;
    int b = g >> 10;
    if (t < KK) {
      int n = idx[(size_t)g * KK + t];
      const float* p = x + ((size_t)b * NN + n) * 3;
      feat[t][0] = p[0] - cent[3 * g];
      feat[t][1] = p[1] - cent[3 * g + 1];
      feat[t][2] = p[2] - cent[3 * g + 2];
      const float* q = pts + ((size_t)b * NN + n) * 3;
      feat[t][3] = q[0];
      feat[t][4] = q[1];
      feat[t][5] = q[2];
    }
    __syncthreads();
    for (int k = kq * 8; k < kq * 8 + 8; ++k) {
      float a = bias1;
#pragma unroll
      for (int j = 0; j < 6; ++j) a += w1r[j] * feat[k][j];
      vT[c1][k] = fmaxf(0.f, a * scale1 + shift1);
    }
    __syncthreads();
    for (int kb = 0; kb < 4; ++kb) {
      int k0 = kh * 16 + kb * 4;
      float a0 = 0.f, a1 = 0.f, a2 = 0.f, a3 = 0.f;
#pragma unroll
      for (int c = 0; c < 64; ++c) {
        float4 v = *(const float4*)&vT[c][k0];
        a0 += w2r[c] * v.x; a1 += w2r[c] * v.y;
        a2 += w2r[c] * v.z; a3 += w2r[c] * v.w;
      }
      a0 += bias2; a1 += bias2; a2 += bias2; a3 += bias2;
      sum += ((a0 + a1) + a2) + a3;
      sq += ((a0 * a0 + a1 * a1) + a2 * a2) + a3 * a3;
    }
    __syncthreads();
  }
  red[c2][kh][0] = sum;
  red[c2][kh][1] = sq;
  __syncthreads();
  if (t < 128) {
    partial2[(size_t)(blockIdx.x * 128 + t) * 2] = red[t][0][0] + red[t][1][0];
    partial2[(size_t)(blockIdx.x * 128 + t) * 2 + 1] = red[t][0][1] + red[t][1][1];
  }
}

// ---------------- finalize BN2 scale/shift ----------------
__global__ void k_red2(const float* __restrict__ partial2,
                       const float* __restrict__ gamma, const float* __restrict__ beta,
                       float* __restrict__ sc2) {
  int c = threadIdx.x;
  if (c >= 128) return;
  double s = 0.0, q = 0.0;
  for (int blk = 0; blk < STAT_BLOCKS; ++blk) {
    s += partial2[(size_t)(blk * 128 + c) * 2];
    q += partial2[(size_t)(blk * 128 + c) * 2 + 1];
  }
  const double cnt = (double)BB * KK * SS;
  double mean = s / cnt;
  double var = q / cnt - mean * mean;
  float scale = gamma[c] * (float)(1.0 / sqrt(var + 1e-5));
  float shift = beta[c] - (float)mean * scale;
  sc2[c] = scale;
  sc2[128 + c] = shift;
}

// ---------------- final: conv1+BN1+ReLU -> conv2+BN2+ReLU -> maxpool ----------------
__global__ __launch_bounds__(256) void k_final(
    const float* __restrict__ x, const float* __restrict__ pts,
    const float* __restrict__ cent, const int* __restrict__ idx,
    const float* __restrict__ w1, const float* __restrict__ b1,
    const float* __restrict__ sc1, const float* __restrict__ w2,
    const float* __restrict__ b2, const float* __restrict__ sc2,
    float* __restrict__ outp) {
  __shared__ float feat[KK][6];
  __shared__ float vT[64][36];
  __shared__ float red[128][2];
  int t = threadIdx.x;
  int c1 = t & 63, kq = t >> 6;
  int c2 = t & 127, kh = t >> 7;
  float w1r[6];
#pragma unroll
  for (int j = 0; j < 6; ++j) w1r[j] = w1[c1 * 6 + j];
  float bias1 = b1[c1];
  float scale1 = sc1[c1], shift1 = sc1[64 + c1];
  float w2r[64];
#pragma unroll
  for (int c = 0; c < 64; ++c) w2r[c] = w2[c2 * 64 + c];
  float bias2 = b2[c2];
  float scale2 = sc2[c2], shift2 = sc2[128 + c2];
  for (int gi = 0; gi < 8; ++gi) {
    int g = blockIdx.x * 8 + gi;
    int b = g >> 10;
    if (t < KK) {
      int n = idx[(size_t)g * KK + t];
      const float* p = x + ((size_t)b * NN + n) * 3;
      feat[t][0] = p[0] - cent[3 * g];
      feat[t][1] = p[1] - cent[3 * g + 1];
      feat[t][2] = p[2] - cent[3 * g + 2];
      const float* q = pts + ((size_t)b * NN + n) * 3;
      feat[t][3] = q[0];
      feat[t][4] = q[1];
      feat[t][5] = q[2];
    }
    __syncthreads();
    for (int k = kq * 8; k < kq * 8 + 8; ++k) {
      float a = bias1;
#pragma unroll
      for (int j = 0; j < 6; ++j) a += w1r[j] * feat[k][j];
      vT[c1][k] = fmaxf(0.f, a * scale1 + shift1);
    }
    __syncthreads();
    float m = -1e30f;
    for (int kb = 0; kb < 4; ++kb) {
      int k0 = kh * 16 + kb * 4;
      float a0 = 0.f, a1 = 0.f, a2 = 0.f, a3 = 0.f;
#pragma unroll
      for (int c = 0; c < 64; ++c) {
        float4 v = *(const float4*)&vT[c][k0];
        a0 += w2r[c] * v.x; a1 += w2r[c] * v.y;
        a2 += w2r[c] * v.z; a3 += w2r[c] * v.w;
      }
      a0 = (a0 + bias2) * scale2 + shift2;
      a1 = (a1 + bias2) * scale2 + shift2;
      a2 = (a2 + bias2) * scale2 + shift2;
      a3 = (a3 + bias2) * scale2 + shift2;
      m = fmaxf(m, fmaxf(fmaxf(a0, a1), fmaxf(a2, a3)));
    }
    red[c2][kh] = m;
    __syncthreads();
    if (t < 128) {
      float mm = fmaxf(red[t][0], red[t][1]);
      outp[(size_t)g * C3 + t] = fmaxf(0.f, mm);  // relu(max)=max(relu)
    }
    __syncthreads();
  }
}

extern "C" void kernel_launch(void* const* d_in, const int* in_sizes, int n_in,
                              void* d_out, int out_size, void* d_ws, size_t ws_size,
                              hipStream_t stream) {
  const float* x      = (const float*)d_in[0];
  const float* pts    = (const float*)d_in[1];
  const float* w1     = (const float*)d_in[2];
  const float* b1     = (const float*)d_in[3];
  const float* gamma1 = (const float*)d_in[4];
  const float* beta1  = (const float*)d_in[5];
  const float* w2     = (const float*)d_in[6];
  const float* b2     = (const float*)d_in[7];
  const float* gamma2 = (const float*)d_in[8];
  const float* beta2  = (const float*)d_in[9];

  float* out_cent = (float*)d_out;                       // [B,S,3]
  float* out_feat = (float*)d_out + (size_t)BB * SS * 3; // [B,S,128]

  char* w = (char*)d_ws;
  int* cidx    = (int*)w;   w += (size_t)BB * SS * 4;
  float* aa    = (float*)w; w += (size_t)BB * SS * 4;
  float* bb    = (float*)w; w += (size_t)BB * NN * 4;
  int* idx     = (int*)w;   w += (size_t)BB * SS * KK * 4;
  float* p1    = (float*)w; w += (size_t)STAT_BLOCKS * 64 * 2 * 4;
  float* p2    = (float*)w; w += (size_t)STAT_BLOCKS * 128 * 2 * 4;
  float* sc1   = (float*)w; w += 64 * 2 * 4;
  float* sc2   = (float*)w; w += 128 * 2 * 4;

  k_bb<<<(BB * NN + 255) / 256, 256, 0, stream>>>(x, bb);
  k_fps<<<BB, 1024, 0, stream>>>(x, cidx);
  k_gather<<<(BB * SS + 255) / 256, 256, 0, stream>>>(x, cidx, out_cent, aa);
  k_ball<<<(BB * SS) / 4, 256, 0, stream>>>(x, out_cent, aa, bb, idx);
  k_stats1<<<STAT_BLOCKS, 256, 0, stream>>>(x, pts, out_cent, idx, w1, b1, p1);
  k_red1<<<1, 64, 0, stream>>>(p1, gamma1, beta1, sc1);
  k_stats2<<<STAT_BLOCKS, 256, 0, stream>>>(x, pts, out_cent, idx, w1, b1, sc1, w2, b2, p2);
  k_red2<<<1, 128, 0, stream>>>(p2, gamma2, beta2, sc2);
  k_final<<<STAT_BLOCKS, 256, 0, stream>>>(x, pts, out_cent, idx, w1, b1, sc1, w2, b2, sc2, out_feat);
}

// Round 3
// 1186.047 us; speedup vs baseline: 2.5448x; 2.5448x over previous
//
#include <hip/hip_runtime.h>
#include <stdint.h>
#include <math.h>

constexpr int BB = 16;      // batch
constexpr int NN = 4096;    // points per batch
constexpr int SS = 1024;    // centroids (N_CENTROIDS)
constexpr int KK = 32;      // NSAMPLES
constexpr int C3 = 128;     // mlp1
constexpr float R2 = 0.25f; // RADIUS^2
constexpr int STAT_BLOCKS = 2048;  // blocks for stats kernels (8 groups each)

// exact-order (a0*a0 + a1*a1) + a2*a2, no fma contraction (matches np sum over 3)
__device__ __forceinline__ float sumsq3(float x, float y, float z) {
#pragma clang fp contract(off)
  return (x * x + y * y) + z * z;
}

// exact-order GEMM-form squared distance: (aa + bb) - 2*((cx*px+cy*py)+cz*pz)
__device__ __forceinline__ float ball_d(float aa, float bb, float cx, float cy,
                                        float cz, float px, float py, float pz) {
#pragma clang fp contract(off)
  float ab = (cx * px + cy * py) + cz * pz;
  return (aa + bb) - 2.0f * ab;
}

// ---------------- bb precompute: per-point squared norms ----------------
__global__ void k_bb(const float* __restrict__ x, float* __restrict__ bb) {
  int i = blockIdx.x * blockDim.x + threadIdx.x;
  if (i >= BB * NN) return;
  float x0 = x[3 * i], x1 = x[3 * i + 1], x2 = x[3 * i + 2];
  bb[i] = sumsq3(x0, x1, x2);
}

// ---------------- FPS: 256 threads, 16 pts/thread in registers, packed-u64 argmax ----------------
__global__ __launch_bounds__(256) void k_fps(const float* __restrict__ x,
                                             int* __restrict__ cidx) {
  __shared__ float xs[NN], ys[NN], zs[NN];
  __shared__ unsigned long long wkey[2][4];
  int b = blockIdx.x, t = threadIdx.x;
  const float* xb = x + (size_t)b * NN * 3;
  float px[16], py[16], pz[16], dmin[16];
#pragma unroll
  for (int j = 0; j < 16; ++j) {
    int n = t + j * 256;
    float a0 = xb[3 * n], a1 = xb[3 * n + 1], a2 = xb[3 * n + 2];
    px[j] = a0; py[j] = a1; pz[j] = a2;
    xs[n] = a0; ys[n] = a1; zs[n] = a2;
    dmin[j] = 1e10f;
  }
  if (t == 0) cidx[b * SS] = 0;
  __syncthreads();
  int far = 0;
  int w = t >> 6;
  for (int it = 1; it < SS; ++it) {
    float cx = xs[far], cy = ys[far], cz = zs[far];
    unsigned long long key = 0ull;
#pragma unroll
    for (int j = 0; j < 16; ++j) {
      int n = t + j * 256;
      float dx = px[j] - cx, dy = py[j] - cy, dz = pz[j] - cz;
      float d = sumsq3(dx, dy, dz);
      float dm = fminf(dmin[j], d);
      dmin[j] = dm;
      // dists >= 0 so f32-bit ordering == uint ordering; lo word = NN-1-n makes
      // max() pick the SMALLEST index on value ties (numpy-first-argmax), order-free.
      unsigned long long k2 =
          ((unsigned long long)__float_as_uint(dm) << 32) | (unsigned)(NN - 1 - n);
      key = (k2 > key) ? k2 : key;
    }
#pragma unroll
    for (int off = 1; off < 64; off <<= 1) {
      unsigned long long ok = __shfl_xor(key, off);
      key = (ok > key) ? ok : key;
    }
    int buf = it & 1;
    if ((t & 63) == 0) wkey[buf][w] = key;
    __syncthreads();
    unsigned long long k0 = wkey[buf][0], k1 = wkey[buf][1];
    unsigned long long k2 = wkey[buf][2], k3 = wkey[buf][3];
    unsigned long long ka = k0 > k1 ? k0 : k1;
    unsigned long long kb = k2 > k3 ? k2 : k3;
    unsigned long long kk = ka > kb ? ka : kb;
    far = NN - 1 - (int)(unsigned)(kk & 0xffffffffu);
    if (t == 0) cidx[b * SS + it] = far;
  }
}

// ---------------- gather centroids to d_out (f32) + squared norms ----------------
__global__ void k_gather(const float* __restrict__ x, const int* __restrict__ cidx,
                         float* __restrict__ outc, float* __restrict__ aa) {
  int i = blockIdx.x * blockDim.x + threadIdx.x;
  if (i >= BB * SS) return;
  int b = i >> 10;
  int n = cidx[i];
  const float* p = x + ((size_t)b * NN + n) * 3;
  float cx = p[0], cy = p[1], cz = p[2];
  outc[3 * i] = cx; outc[3 * i + 1] = cy; outc[3 * i + 2] = cz;
  aa[i] = sumsq3(cx, cy, cz);
}

// ---------------- ball query: one wave per (b,s) ----------------
__global__ __launch_bounds__(256) void k_ball(const float* __restrict__ x,
                                              const float* __restrict__ cent,
                                              const float* __restrict__ aa,
                                              const float* __restrict__ bb,
                                              int* __restrict__ idx) {
  int gw = (blockIdx.x * 256 + threadIdx.x) >> 6;  // 0..16383
  int lane = threadIdx.x & 63;
  if (gw >= BB * SS) return;
  int b = gw >> 10;
  const float* xb = x + (size_t)b * NN * 3;
  const float* bbb = bb + b * NN;
  float cx = cent[3 * gw], cy = cent[3 * gw + 1], cz = cent[3 * gw + 2];
  float a = aa[gw];
  int* out = idx + (size_t)gw * KK;
  int found = 0, firstN = 0;
  for (int c0 = 0; c0 < NN && found < KK; c0 += 64) {
    int n = c0 + lane;
    float px = xb[3 * n], py = xb[3 * n + 1], pz = xb[3 * n + 2];
    float d = ball_d(a, bbb[n], cx, cy, cz, px, py, pz);
    bool pred = (d <= R2);  // reference excludes d > r^2
    unsigned long long m = __ballot(pred);
    if (found == 0 && m) firstN = c0 + (__ffsll((unsigned long long)m) - 1);
    if (pred) {
      int pos = found + __popcll(m & ((1ull << lane) - 1ull));
      if (pos < KK) out[pos] = n;
    }
    found += __popcll(m);
  }
  if (lane == 0 && found < KK) {
    for (int k = found; k < KK; ++k) out[k] = firstN;
  }
}

// ---------------- stats for BN1: conv1 over all groups, per-channel sum/sumsq ----------------
__global__ __launch_bounds__(256) void k_stats1(
    const float* __restrict__ x, const float* __restrict__ pts,
    const float* __restrict__ cent, const int* __restrict__ idx,
    const float* __restrict__ w1, const float* __restrict__ b1,
    float* __restrict__ partial1) {
  __shared__ float feat[KK][6];
  __shared__ float red[4][64][2];
  int t = threadIdx.x;
  int c = t & 63, kq = t >> 6;
  float w[6];
#pragma unroll
  for (int j = 0; j < 6; ++j) w[j] = w1[c * 6 + j];
  float bias = b1[c];
  float sum = 0.f, sq = 0.f;
  for (int gi = 0; gi < 8; ++gi) {
    int g = blockIdx.x * 8 + gi;
    int b = g >> 10;
    if (t < KK) {
      int n = idx[(size_t)g * KK + t];
      const float* p = x + ((size_t)b * NN + n) * 3;
      feat[t][0] = p[0] - cent[3 * g];
      feat[t][1] = p[1] - cent[3 * g + 1];
      feat[t][2] = p[2] - cent[3 * g + 2];
      const float* q = pts + ((size_t)b * NN + n) * 3;
      feat[t][3] = q[0];
      feat[t][4] = q[1];
      feat[t][5] = q[2];
    }
    __syncthreads();
    for (int k = kq * 8; k < kq * 8 + 8; ++k) {
      float a = bias;
#pragma unroll
      for (int j = 0; j < 6; ++j) a += w[j] * feat[k][j];
      sum += a;
      sq += a * a;
    }
    __syncthreads();
  }
  red[kq][c][0] = sum;
  red[kq][c][1] = sq;
  __syncthreads();
  if (t < 64) {
    float s = ((red[0][t][0] + red[1][t][0]) + red[2][t][0]) + red[3][t][0];
    float q = ((red[0][t][1] + red[1][t][1]) + red[2][t][1]) + red[3][t][1];
    partial1[(size_t)(blockIdx.x * 64 + t) * 2] = s;
    partial1[(size_t)(blockIdx.x * 64 + t) * 2 + 1] = q;
  }
}

// ---------------- finalize BN1 scale/shift (4-way parallel over blocks) ----------------
__global__ void k_red1(const float* __restrict__ partial1,
                       const float* __restrict__ gamma, const float* __restrict__ beta,
                       float* __restrict__ sc1) {
  __shared__ double rd[64][4][2];
  int t = threadIdx.x;  // 256
  int c = t & 63, q = t >> 6;
  double s = 0.0, qq = 0.0;
  for (int blk = q * 512; blk < q * 512 + 512; ++blk) {
    s += partial1[(size_t)(blk * 64 + c) * 2];
    qq += partial1[(size_t)(blk * 64 + c) * 2 + 1];
  }
  rd[c][q][0] = s; rd[c][q][1] = qq;
  __syncthreads();
  if (t < 64) {
    double S = ((rd[t][0][0] + rd[t][1][0]) + rd[t][2][0]) + rd[t][3][0];
    double Q = ((rd[t][0][1] + rd[t][1][1]) + rd[t][2][1]) + rd[t][3][1];
    const double cnt = (double)BB * KK * SS;
    double mean = S / cnt;
    double var = Q / cnt - mean * mean;
    float scale = gamma[t] * (float)(1.0 / sqrt(var + 1e-5));
    float shift = beta[t] - (float)mean * scale;
    sc1[t] = scale;
    sc1[64 + t] = shift;
  }
}

// ---------------- stats for BN2: conv1+BN1+ReLU, conv2 (2 c2 x 8 k / thread) ----------------
__global__ __launch_bounds__(256, 2) void k_stats2(
    const float* __restrict__ x, const float* __restrict__ pts,
    const float* __restrict__ cent, const int* __restrict__ idx,
    const float* __restrict__ w1, const float* __restrict__ b1,
    const float* __restrict__ sc1, const float* __restrict__ w2,
    const float* __restrict__ b2, float* __restrict__ partial2) {
  __shared__ float feat[KK][6];
  __shared__ float vT[64][36];   // [c1][k], padded rows
  __shared__ float red[C3][4][2];
  int t = threadIdx.x;
  int c1 = t & 63, kq = t >> 6;
  int c2p = t >> 2, ks = t & 3;   // channel pair {c2p, c2p+64}, k-slot of 8
  float w1r[6];
#pragma unroll
  for (int j = 0; j < 6; ++j) w1r[j] = w1[c1 * 6 + j];
  float bias1 = b1[c1];
  float scale1 = sc1[c1], shift1 = sc1[64 + c1];
  float w2a[64], w2b[64];
#pragma unroll
  for (int c = 0; c < 64; ++c) {
    w2a[c] = w2[c2p * 64 + c];
    w2b[c] = w2[(c2p + 64) * 64 + c];
  }
  float bias2a = b2[c2p], bias2b = b2[c2p + 64];
  float sumA = 0.f, sqA = 0.f, sumB = 0.f, sqB = 0.f;
  for (int gi = 0; gi < 8; ++gi) {
    int g = blockIdx.x * 8 + gi;
    int b = g >> 10;
    if (t < KK) {
      int n = idx[(size_t)g * KK + t];
      const float* p = x + ((size_t)b * NN + n) * 3;
      feat[t][0] = p[0] - cent[3 * g];
      feat[t][1] = p[1] - cent[3 * g + 1];
      feat[t][2] = p[2] - cent[3 * g + 2];
      const float* q = pts + ((size_t)b * NN + n) * 3;
      feat[t][3] = q[0];
      feat[t][4] = q[1];
      feat[t][5] = q[2];
    }
    __syncthreads();  // (A) feat ready; also guards vT overwrite vs prev conv2 readers
    for (int k = kq * 8; k < kq * 8 + 8; ++k) {
      float a = bias1;
#pragma unroll
      for (int j = 0; j < 6; ++j) a += w1r[j] * feat[k][j];
      vT[c1][k] = fmaxf(0.f, a * scale1 + shift1);
    }
    __syncthreads();  // (B) vT ready
    float accA[8] = {0, 0, 0, 0, 0, 0, 0, 0};
    float accB[8] = {0, 0, 0, 0, 0, 0, 0, 0};
#pragma unroll
    for (int c = 0; c < 64; ++c) {
      float4 v0 = *(const float4*)&vT[c][ks * 8];
      float4 v1 = *(const float4*)&vT[c][ks * 8 + 4];
      float wa = w2a[c], wb = w2b[c];
      accA[0] += wa * v0.x; accA[1] += wa * v0.y; accA[2] += wa * v0.z; accA[3] += wa * v0.w;
      accA[4] += wa * v1.x; accA[5] += wa * v1.y; accA[6] += wa * v1.z; accA[7] += wa * v1.w;
      accB[0] += wb * v0.x; accB[1] += wb * v0.y; accB[2] += wb * v0.z; accB[3] += wb * v0.w;
      accB[4] += wb * v1.x; accB[5] += wb * v1.y; accB[6] += wb * v1.z; accB[7] += wb * v1.w;
    }
#pragma unroll
    for (int i = 0; i < 8; ++i) {
      float a = accA[i] + bias2a;
      sumA += a; sqA += a * a;
      float c_ = accB[i] + bias2b;
      sumB += c_; sqB += c_ * c_;
    }
  }
  red[c2p][ks][0] = sumA; red[c2p][ks][1] = sqA;
  red[c2p + 64][ks][0] = sumB; red[c2p + 64][ks][1] = sqB;
  __syncthreads();
  if (t < C3) {
    float s = ((red[t][0][0] + red[t][1][0]) + red[t][2][0]) + red[t][3][0];
    float q = ((red[t][0][1] + red[t][1][1]) + red[t][2][1]) + red[t][3][1];
    partial2[(size_t)(blockIdx.x * 128 + t) * 2] = s;
    partial2[(size_t)(blockIdx.x * 128 + t) * 2 + 1] = q;
  }
}

// ---------------- finalize BN2 scale/shift (4-way parallel over blocks) ----------------
__global__ void k_red2(const float* __restrict__ partial2,
                       const float* __restrict__ gamma, const float* __restrict__ beta,
                       float* __restrict__ sc2) {
  __shared__ double rd[128][4][2];
  int t = threadIdx.x;  // 512
  int c = t & 127, q = t >> 7;
  double s = 0.0, qq = 0.0;
  for (int blk = q * 512; blk < q * 512 + 512; ++blk) {
    s += partial2[(size_t)(blk * 128 + c) * 2];
    qq += partial2[(size_t)(blk * 128 + c) * 2 + 1];
  }
  rd[c][q][0] = s; rd[c][q][1] = qq;
  __syncthreads();
  if (t < 128) {
    double S = ((rd[t][0][0] + rd[t][1][0]) + rd[t][2][0]) + rd[t][3][0];
    double Q = ((rd[t][0][1] + rd[t][1][1]) + rd[t][2][1]) + rd[t][3][1];
    const double cnt = (double)BB * KK * SS;
    double mean = S / cnt;
    double var = Q / cnt - mean * mean;
    float scale = gamma[t] * (float)(1.0 / sqrt(var + 1e-5));
    float shift = beta[t] - (float)mean * scale;
    sc2[t] = scale;
    sc2[128 + t] = shift;
  }
}

// ---------------- final: conv1+BN1+ReLU -> conv2+BN2+ReLU -> maxpool ----------------
__global__ __launch_bounds__(256, 2) void k_final(
    const float* __restrict__ x, const float* __restrict__ pts,
    const float* __restrict__ cent, const int* __restrict__ idx,
    const float* __restrict__ w1, const float* __restrict__ b1,
    const float* __restrict__ sc1, const float* __restrict__ w2,
    const float* __restrict__ b2, const float* __restrict__ sc2,
    float* __restrict__ outp) {
  __shared__ float feat[KK][6];
  __shared__ float vT[64][36];
  __shared__ float red[C3][4];
  int t = threadIdx.x;
  int c1 = t & 63, kq = t >> 6;
  int c2p = t >> 2, ks = t & 3;
  float w1r[6];
#pragma unroll
  for (int j = 0; j < 6; ++j) w1r[j] = w1[c1 * 6 + j];
  float bias1 = b1[c1];
  float scale1 = sc1[c1], shift1 = sc1[64 + c1];
  float w2a[64], w2b[64];
#pragma unroll
  for (int c = 0; c < 64; ++c) {
    w2a[c] = w2[c2p * 64 + c];
    w2b[c] = w2[(c2p + 64) * 64 + c];
  }
  float bias2a = b2[c2p], bias2b = b2[c2p + 64];
  float scale2a = sc2[c2p], shift2a = sc2[128 + c2p];
  float scale2b = sc2[c2p + 64], shift2b = sc2[128 + c2p + 64];
  for (int gi = 0; gi < 8; ++gi) {
    int g = blockIdx.x * 8 + gi;
    int b = g >> 10;
    if (t < KK) {
      int n = idx[(size_t)g * KK + t];
      const float* p = x + ((size_t)b * NN + n) * 3;
      feat[t][0] = p[0] - cent[3 * g];
      feat[t][1] = p[1] - cent[3 * g + 1];
      feat[t][2] = p[2] - cent[3 * g + 2];
      const float* q = pts + ((size_t)b * NN + n) * 3;
      feat[t][3] = q[0];
      feat[t][4] = q[1];
      feat[t][5] = q[2];
    }
    __syncthreads();  // (A)
    for (int k = kq * 8; k < kq * 8 + 8; ++k) {
      float a = bias1;
#pragma unroll
      for (int j = 0; j < 6; ++j) a += w1r[j] * feat[k][j];
      vT[c1][k] = fmaxf(0.f, a * scale1 + shift1);
    }
    __syncthreads();  // (B)
    float accA[8] = {0, 0, 0, 0, 0, 0, 0, 0};
    float accB[8] = {0, 0, 0, 0, 0, 0, 0, 0};
#pragma unroll
    for (int c = 0; c < 64; ++c) {
      float4 v0 = *(const float4*)&vT[c][ks * 8];
      float4 v1 = *(const float4*)&vT[c][ks * 8 + 4];
      float wa = w2a[c], wb = w2b[c];
      accA[0] += wa * v0.x; accA[1] += wa * v0.y; accA[2] += wa * v0.z; accA[3] += wa * v0.w;
      accA[4] += wa * v1.x; accA[5] += wa * v1.y; accA[6] += wa * v1.z; accA[7] += wa * v1.w;
      accB[0] += wb * v0.x; accB[1] += wb * v0.y; accB[2] += wb * v0.z; accB[3] += wb * v0.w;
      accB[4] += wb * v1.x; accB[5] += wb * v1.y; accB[6] += wb * v1.z; accB[7] += wb * v1.w;
    }
    float mA = -1e30f, mB = -1e30f;
#pragma unroll
    for (int i = 0; i < 8; ++i) {
      mA = fmaxf(mA, (accA[i] + bias2a) * scale2a + shift2a);
      mB = fmaxf(mB, (accB[i] + bias2b) * scale2b + shift2b);
    }
    red[c2p][ks] = mA;
    red[c2p + 64][ks] = mB;
    __syncthreads();  // (C) red ready
    if (t < C3) {
      float mm = fmaxf(fmaxf(red[t][0], red[t][1]), fmaxf(red[t][2], red[t][3]));
      outp[(size_t)g * C3 + t] = fmaxf(0.f, mm);  // relu(max)=max(relu)
    }
  }
}

extern "C" void kernel_launch(void* const* d_in, const int* in_sizes, int n_in,
                              void* d_out, int out_size, void* d_ws, size_t ws_size,
                              hipStream_t stream) {
  const float* x      = (const float*)d_in[0];
  const float* pts    = (const float*)d_in[1];
  const float* w1     = (const float*)d_in[2];
  const float* b1     = (const float*)d_in[3];
  const float* gamma1 = (const float*)d_in[4];
  const float* beta1  = (const float*)d_in[5];
  const float* w2     = (const float*)d_in[6];
  const float* b2     = (const float*)d_in[7];
  const float* gamma2 = (const float*)d_in[8];
  const float* beta2  = (const float*)d_in[9];

  float* out_cent = (float*)d_out;                       // [B,S,3]
  float* out_feat = (float*)d_out + (size_t)BB * SS * 3; // [B,S,128]

  char* w = (char*)d_ws;
  int* cidx    = (int*)w;   w += (size_t)BB * SS * 4;
  float* aa    = (float*)w; w += (size_t)BB * SS * 4;
  float* bb    = (float*)w; w += (size_t)BB * NN * 4;
  int* idx     = (int*)w;   w += (size_t)BB * SS * KK * 4;
  float* p1    = (float*)w; w += (size_t)STAT_BLOCKS * 64 * 2 * 4;
  float* p2    = (float*)w; w += (size_t)STAT_BLOCKS * 128 * 2 * 4;
  float* sc1   = (float*)w; w += 64 * 2 * 4;
  float* sc2   = (float*)w; w += 128 * 2 * 4;

  k_bb<<<(BB * NN + 255) / 256, 256, 0, stream>>>(x, bb);
  k_fps<<<BB, 256, 0, stream>>>(x, cidx);
  k_gather<<<(BB * SS + 255) / 256, 256, 0, stream>>>(x, cidx, out_cent, aa);
  k_ball<<<(BB * SS) / 4, 256, 0, stream>>>(x, out_cent, aa, bb, idx);
  k_stats1<<<STAT_BLOCKS, 256, 0, stream>>>(x, pts, out_cent, idx, w1, b1, p1);
  k_red1<<<1, 256, 0, stream>>>(p1, gamma1, beta1, sc1);
  k_stats2<<<STAT_BLOCKS, 256, 0, stream>>>(x, pts, out_cent, idx, w1, b1, sc1, w2, b2, p2);
  k_red2<<<1, 512, 0, stream>>>(p2, gamma2, beta2, sc2);
  k_final<<<STAT_BLOCKS, 256, 0, stream>>>(x, pts, out_cent, idx, w1, b1, sc1, w2, b2, sc2, out_feat);
}